// Round 4
// baseline (355.629 us; speedup 1.0000x reference)
//
#include <hip/hip_runtime.h>
#include <hip/hip_bf16.h>
#include <math.h>

#define SS 200
#define BB 1024
#define DD 128
#define FF 512
#define LL1 80
#define LL2 40
#define PP (SS*BB)            // 204800 flattened (s,b) pairs
#define MASK_FILL_F (-4294967295.0f)

typedef short bf16x8 __attribute__((ext_vector_type(8)));
typedef float f32x4  __attribute__((ext_vector_type(4)));

static __device__ __forceinline__ unsigned short f2bf(float x) {
    __hip_bfloat16 h = __float2bfloat16(x);
    return *reinterpret_cast<unsigned short*>(&h);
}
static __device__ __forceinline__ float bf2f(unsigned short u) {
    __hip_bfloat16 h = *reinterpret_cast<__hip_bfloat16*>(&u);
    return __bfloat162float(h);
}
// truncation split: hi = top 16 bits, lo = bf16(x - hi). |err| ~ 2^-16 rel.
static __device__ __forceinline__ void split8(const float* x, bf16x8& ah, bf16x8& al) {
#pragma unroll
    for (int j = 0; j < 8; ++j) {
        unsigned u = __float_as_uint(x[j]);
        ah[j] = (short)(u >> 16);
        float hi = __uint_as_float(u & 0xffff0000u);
        al[j] = (short)f2bf(x[j] - hi);
    }
}

// ---------------------------------------------------------------------------
// Merged prep: block 35 = mask-layout detect; blocks 0-29 = W1 fold+split to
// MFMA B-frags; blocks 30-34 = W2 pad+split.
// bfr1[(((seg*2+hl)*4 + kt)*5 + nt)*64 + lane][8]; B[k][n]: n=nt*16+(lane&15),
// k=kt*32+(lane>>4)*8+j.  bfr2 frag id (kt*3+nt)*2+hl.
__global__ void k_prep_all(const float* __restrict__ W1, const float* __restrict__ W2,
                           const unsigned char* __restrict__ mask,
                           unsigned short* __restrict__ bfr1,
                           unsigned short* __restrict__ bfr2, int* __restrict__ flag) {
    const int blk = blockIdx.x;
    if (blk == 35) {
        if (threadIdx.x == 0) {
            int f = 0;
            for (int i = 0; i < 256; ++i)
                if ((i & 3) && mask[i]) f = 1;
            *flag = f;
        }
        return;
    }
    if (blk < 30) {
        int t = blk * 256 + threadIdx.x;
        if (t >= 120 * 64) return;
        int lane = t & 63;
        int fid  = t >> 6;
        int nt   = fid % 5;
        int kt   = (fid / 5) & 3;
        int hl   = (fid / 20) & 1;
        int seg  = fid / 40;
        int n     = nt * 16 + (lane & 15);
        int kbase = kt * 32 + (lane >> 4) * 8;
        unsigned short* o = bfr1 + (size_t)t * 8;
#pragma unroll
        for (int j = 0; j < 8; ++j) {
            int k = kbase + j;
            float w;
            if (seg == 0)      w = W1[k * LL1 + n] + W1[(384 + k) * LL1 + n];
            else if (seg == 1) w = W1[(128 + k) * LL1 + n] - W1[(384 + k) * LL1 + n];
            else               w = W1[(256 + k) * LL1 + n];
            unsigned short hb = f2bf(w);
            o[j] = (hl == 0) ? hb : f2bf(w - bf2f(hb));
        }
    } else {
        int t = (blk - 30) * 256 + threadIdx.x;
        if (t >= 18 * 64) return;
        int lane = t & 63;
        int fid  = t >> 6;
        int hl   = fid & 1;
        int nt   = (fid >> 1) % 3;
        int kt   = fid / 6;
        int n  = nt * 16 + (lane & 15);
        int kb = kt * 32 + (lane >> 4) * 8;
        unsigned short* o = bfr2 + (size_t)t * 8;
#pragma unroll
        for (int j = 0; j < 8; ++j) {
            int k = kb + j;
            float w = (k < LL1 && n < LL2) ? W2[k * LL2 + n] : 0.f;
            unsigned short hb = f2bf(w);
            o[j] = (hl == 0) ? hb : f2bf(w - bf2f(hb));
        }
    }
}

// ---------------------------------------------------------------------------
// K1: z1[p][l] = q·Wq + f·Wf + (q*f)·Wc + b1 via split-bf16 MFMA 16x16x32.
// t=2 row-tiles (32 rows/wave), grid 1600, fully unrolled K-loop, VGPR<=168.
__global__ __launch_bounds__(256, 3) void k1_mfma(
    const float* __restrict__ query, const float* __restrict__ facts,
    const unsigned short* __restrict__ bfr, const float* __restrict__ b1,
    float* __restrict__ z1) {
    const int tid  = threadIdx.x;
    const int lane = tid & 63;
    const int m    = lane & 15;
    const int quad = lane >> 4;
    const int pw   = blockIdx.x * 128 + (tid >> 6) * 32;

    f32x4 acc[2][5];
#pragma unroll
    for (int t = 0; t < 2; ++t)
#pragma unroll
        for (int nt = 0; nt < 5; ++nt) acc[t][nt] = (f32x4){0.f, 0.f, 0.f, 0.f};

    int pr[2], qr[2];
#pragma unroll
    for (int t = 0; t < 2; ++t) {
        pr[t] = pw + t * 16 + m;
        qr[t] = pr[t] / SS;
    }

#pragma unroll
    for (int kt = 0; kt < 4; ++kt) {
        const int dbase = kt * 32 + quad * 8;
        float q8[2][8], f8[2][8];
#pragma unroll
        for (int t = 0; t < 2; ++t) {
            *(float4*)&q8[t][0] = *(const float4*)(query + (size_t)qr[t] * DD + dbase);
            *(float4*)&q8[t][4] = *(const float4*)(query + (size_t)qr[t] * DD + dbase + 4);
            *(float4*)&f8[t][0] = *(const float4*)(facts + (size_t)pr[t] * DD + dbase);
            *(float4*)&f8[t][4] = *(const float4*)(facts + (size_t)pr[t] * DD + dbase + 4);
        }
#pragma unroll
        for (int seg = 0; seg < 3; ++seg) {
            bf16x8 Bh[5], Bl[5];
            const unsigned short* bh0 = bfr + ((((size_t)(seg * 2 + 0) * 4 + kt) * 5) * 64 + lane) * 8;
            const unsigned short* bl0 = bfr + ((((size_t)(seg * 2 + 1) * 4 + kt) * 5) * 64 + lane) * 8;
#pragma unroll
            for (int nt = 0; nt < 5; ++nt) {
                Bh[nt] = *(const bf16x8*)(bh0 + (size_t)nt * 512);
                Bl[nt] = *(const bf16x8*)(bl0 + (size_t)nt * 512);
            }
            bf16x8 ah[2], al[2];
#pragma unroll
            for (int t = 0; t < 2; ++t) {
                float x8[8];
#pragma unroll
                for (int j = 0; j < 8; ++j)
                    x8[j] = (seg == 0) ? q8[t][j] : (seg == 1 ? f8[t][j] : q8[t][j] * f8[t][j]);
                split8(x8, ah[t], al[t]);
            }
#pragma unroll
            for (int t = 0; t < 2; ++t)
#pragma unroll
                for (int nt = 0; nt < 5; ++nt) {
                    acc[t][nt] = __builtin_amdgcn_mfma_f32_16x16x32_bf16(ah[t], Bh[nt], acc[t][nt], 0, 0, 0);
                    acc[t][nt] = __builtin_amdgcn_mfma_f32_16x16x32_bf16(al[t], Bh[nt], acc[t][nt], 0, 0, 0);
                    acc[t][nt] = __builtin_amdgcn_mfma_f32_16x16x32_bf16(ah[t], Bl[nt], acc[t][nt], 0, 0, 0);
                }
        }
    }
    // C/D layout: col = lane&15, row = quad*4 + reg
#pragma unroll
    for (int t = 0; t < 2; ++t)
#pragma unroll
        for (int nt = 0; nt < 5; ++nt) {
            int n = nt * 16 + m;
            float bias = b1[n];
#pragma unroll
            for (int r = 0; r < 4; ++r)
                z1[(size_t)(pw + t * 16 + quad * 4 + r) * LL1 + n] = acc[t][nt][r] + bias;
        }
}

// ---------------------------------------------------------------------------
// Stats for z1: per-(b,l) column sum/sumsq over s via atomics. grid (320, 8).
__global__ __launch_bounds__(256) void k_stats(
    const float* __restrict__ z, int C,
    float* __restrict__ sum, float* __restrict__ sumsq) {
    int col = blockIdx.x * 256 + threadIdx.x;
    int s0  = blockIdx.y * 25;
    const float* pz = z + (size_t)s0 * C + col;
    float ps = 0.f, pss = 0.f;
#pragma unroll 5
    for (int i = 0; i < 25; ++i) {
        float v = pz[(size_t)i * C];
        ps += v;
        pss = fmaf(v, v, pss);
    }
    atomicAdd(&sum[col], ps);
    atomicAdd(&sumsq[col], pss);
}

// ---------------------------------------------------------------------------
// K2: dice1-on-load + split-bf16 MFMA GEMM (K 80->96, N 40->48).
// t=2 (32 rows/wave), grid 1600; all 18 W2 frags in registers.
// Output TRANSPOSED: z2T[b][s][l].
__global__ __launch_bounds__(256, 3) void k2_mfma(
    const float* __restrict__ z1, const float* __restrict__ sum1,
    const float* __restrict__ sumsq1, const float* __restrict__ a1,
    const unsigned short* __restrict__ bfr2, const float* __restrict__ b2,
    float* __restrict__ z2T) {
    const int tid  = threadIdx.x;
    const int lane = tid & 63;
    const int m    = lane & 15;
    const int quad = lane >> 4;
    const int pw   = blockIdx.x * 128 + (tid >> 6) * 32;
    const float alpha = *a1;

    bf16x8 Bh[3][3], Bl[3][3];
#pragma unroll
    for (int kt = 0; kt < 3; ++kt)
#pragma unroll
        for (int nt = 0; nt < 3; ++nt) {
            Bh[kt][nt] = *(const bf16x8*)(bfr2 + (((size_t)(kt * 3 + nt) * 2 + 0) * 64 + lane) * 8);
            Bl[kt][nt] = *(const bf16x8*)(bfr2 + (((size_t)(kt * 3 + nt) * 2 + 1) * 64 + lane) * 8);
        }
    float b2v[3];
#pragma unroll
    for (int nt = 0; nt < 3; ++nt) {
        int n = nt * 16 + m;
        b2v[nt] = (n < LL2) ? b2[n] : 0.f;
    }

#pragma unroll
    for (int t = 0; t < 2; ++t) {
        const int p = pw + t * 16 + m;
        const int b = p & (BB - 1);
        f32x4 acc[3];
#pragma unroll
        for (int nt = 0; nt < 3; ++nt) acc[nt] = (f32x4){0.f, 0.f, 0.f, 0.f};

#pragma unroll
        for (int kt = 0; kt < 3; ++kt) {
            float x8[8];
            const int kb = kt * 32 + quad * 8;
            if (kt < 2 || quad < 2) {
                const float* zr = z1     + (size_t)p * LL1 + kb;
                const float* su = sum1   + (size_t)b * LL1 + kb;
                const float* sq = sumsq1 + (size_t)b * LL1 + kb;
                float vv[8], sv[8], qv[8];
                *(float4*)&vv[0] = *(const float4*)zr;
                *(float4*)&vv[4] = *(const float4*)(zr + 4);
                *(float4*)&sv[0] = *(const float4*)su;
                *(float4*)&sv[4] = *(const float4*)(su + 4);
                *(float4*)&qv[0] = *(const float4*)sq;
                *(float4*)&qv[4] = *(const float4*)(sq + 4);
#pragma unroll
                for (int j = 0; j < 8; ++j) {
                    float mean = sv[j] * (1.f / SS);
                    float var  = (qv[j] - (float)SS * mean * mean) * (1.f / (SS - 1));
                    float istd = rsqrtf(var);
                    float pp   = 1.f / (1.f + expf(-(vv[j] - mean) * istd));
                    x8[j] = vv[j] * (pp + alpha * (1.f - pp));
                }
            } else {
#pragma unroll
                for (int j = 0; j < 8; ++j) x8[j] = 0.f;
            }
            bf16x8 ah, al;
            split8(x8, ah, al);
#pragma unroll
            for (int nt = 0; nt < 3; ++nt) {
                acc[nt] = __builtin_amdgcn_mfma_f32_16x16x32_bf16(ah, Bh[kt][nt], acc[nt], 0, 0, 0);
                acc[nt] = __builtin_amdgcn_mfma_f32_16x16x32_bf16(al, Bh[kt][nt], acc[nt], 0, 0, 0);
                acc[nt] = __builtin_amdgcn_mfma_f32_16x16x32_bf16(ah, Bl[kt][nt], acc[nt], 0, 0, 0);
            }
        }
#pragma unroll
        for (int r = 0; r < 4; ++r) {
            const int prow = pw + t * 16 + quad * 4 + r;
            const int br = prow & (BB - 1);
            const int sr = prow >> 10;
            float* o = z2T + (size_t)br * (SS * LL2) + (size_t)sr * LL2;
#pragma unroll
            for (int nt = 0; nt < 3; ++nt) {
                int n = nt * 16 + m;
                if (n < LL2) o[n] = acc[nt][r] + b2v[nt];
            }
        }
    }
}

// ---------------------------------------------------------------------------
// K3: per b: stage z2T[b] (200x40) to LDS, parallel in-block stats over s,
// dice2, W3 dot, masked softmax over s -> wbufT[b][s].
__global__ __launch_bounds__(256) void k3_fused(
    const float* __restrict__ z2T, const float* __restrict__ a2,
    const float* __restrict__ W3, const float* __restrict__ b3,
    const void* __restrict__ mask, const int* __restrict__ flag,
    float* __restrict__ wbufT) {
    const int b   = blockIdx.x;
    const int tid = threadIdx.x;
    __shared__ float lds[SS * 41];       // stride 41: conflict-free both phases
    __shared__ float psum[6 * LL2], pssq[6 * LL2];
    __shared__ float smean[LL2], sistd[LL2], sw3[LL2];
    __shared__ float red[4];

    const float4* src = (const float4*)(z2T + (size_t)b * (SS * LL2));
    for (int i = tid; i < (SS * LL2) / 4; i += 256) {
        float4 v = src[i];
        int s = i / 10;
        int o = (i - s * 10) * 4;
        float* d = &lds[s * 41 + o];
        d[0] = v.x; d[1] = v.y; d[2] = v.z; d[3] = v.w;
    }
    __syncthreads();
    // parallel stats: 240 threads = 6 s-chunks x 40 cols
    if (tid < 240) {
        int l = tid % LL2, c = tid / LL2;
        int s0 = c * 34, s1 = (c == 5) ? SS : s0 + 34;
        float sum = 0.f, ssq = 0.f;
        for (int s = s0; s < s1; ++s) {
            float v = lds[s * 41 + l];
            sum += v;
            ssq = fmaf(v, v, ssq);
        }
        psum[c * LL2 + l] = sum;
        pssq[c * LL2 + l] = ssq;
    }
    __syncthreads();
    if (tid < LL2) {
        float sum = 0.f, ssq = 0.f;
#pragma unroll
        for (int c = 0; c < 6; ++c) {
            sum += psum[c * LL2 + tid];
            ssq += pssq[c * LL2 + tid];
        }
        float mean = sum * (1.f / SS);
        float var  = (ssq - (float)SS * mean * mean) * (1.f / (SS - 1));
        smean[tid] = mean;
        sistd[tid] = rsqrtf(var);
        sw3[tid]   = W3[tid];
    }
    __syncthreads();
    const float alpha = *a2;
    const int boolLayout = *flag;

    float logit = -3.0e38f;
    if (tid < SS) {
        float dot = b3[0];
#pragma unroll
        for (int k = 0; k < LL2; ++k) {
            float v  = lds[tid * 41 + k];
            float pp = 1.f / (1.f + expf(-(v - smean[k]) * sistd[k]));
            float h  = v * (pp + alpha * (1.f - pp));
            dot = fmaf(h, sw3[k], dot);
        }
        int mi = tid * BB + b;
        bool mk = boolLayout ? (((const unsigned char*)mask)[mi] != 0)
                             : (((const int*)mask)[mi] != 0);
        logit = mk ? dot : MASK_FILL_F;
    }
    float v = logit;
#pragma unroll
    for (int off = 1; off < 64; off <<= 1) v = fmaxf(v, __shfl_xor(v, off, 64));
    if ((tid & 63) == 0) red[tid >> 6] = v;
    __syncthreads();
    float smax = fmaxf(fmaxf(red[0], red[1]), fmaxf(red[2], red[3]));
    __syncthreads();
    float e = (tid < SS) ? expf(logit - smax) : 0.f;
    v = e;
#pragma unroll
    for (int off = 1; off < 64; off <<= 1) v += __shfl_xor(v, off, 64);
    if ((tid & 63) == 0) red[tid >> 6] = v;
    __syncthreads();
    float inv = 1.f / (red[0] + red[1] + red[2] + red[3]);
    if (tid < SS) wbufT[(size_t)b * SS + tid] = e * inv;
}

// ---------------------------------------------------------------------------
// K4: out[s][b][d] = wbufT[b][s] * facts[s][b][d]
__global__ __launch_bounds__(256) void k4_scale(
    const float* __restrict__ wbufT, const float* __restrict__ facts,
    float* __restrict__ out) {
    int i = blockIdx.x * 256 + threadIdx.x;   // float4 index
    int p = i >> 5;                           // (s*B + b), 32 float4 per row
    float w = wbufT[(size_t)(p & (BB - 1)) * SS + (p >> 10)];
    float4 f = ((const float4*)facts)[i];
    float4 o;
    o.x = f.x * w; o.y = f.y * w; o.z = f.z * w; o.w = f.w * w;
    ((float4*)out)[i] = o;
}

// ---------------------------------------------------------------------------
extern "C" void kernel_launch(void* const* d_in, const int* in_sizes, int n_in,
                              void* d_out, int out_size, void* d_ws, size_t ws_size,
                              hipStream_t stream) {
    const float* query = (const float*)d_in[0];
    const float* facts = (const float*)d_in[1];
    const void*  mask  = d_in[2];
    const float* W1 = (const float*)d_in[3];
    const float* b1 = (const float*)d_in[4];
    const float* a1 = (const float*)d_in[5];
    const float* W2 = (const float*)d_in[6];
    const float* b2 = (const float*)d_in[7];
    const float* a2 = (const float*)d_in[8];
    const float* W3 = (const float*)d_in[9];
    const float* b3 = (const float*)d_in[10];
    float* out = (float*)d_out;

    // d_out scratch (26,214,400 floats; all dead before k4 overwrites):
    //   z1 [0, 16,384,000) ; z2T [16,384,000, 24,576,000) (layout [b][s][l])
    //   sum1 @24,576,000 ; sumsq1 @24,657,920 ; bfr1 @24,739,840 ; bfr2 @24,801,280
    float* z1  = out;
    float* z2T = out + (size_t)PP * LL1;
    float* sum1   = out + 24576000;
    float* sumsq1 = out + 24657920;
    unsigned short* bfr1 = (unsigned short*)(out + 24739840);
    unsigned short* bfr2 = (unsigned short*)(out + 24801280);
    float* wbufT = (float*)d_ws;
    int*   flag  = (int*)((char*)d_ws + 900 * 1024);

    k_prep_all<<<36, 256, 0, stream>>>(W1, W2, (const unsigned char*)mask, bfr1, bfr2, flag);
    hipMemsetAsync(sum1, 0, 163840 * sizeof(float), stream);
    k1_mfma<<<PP / 128, 256, 0, stream>>>(query, facts, bfr1, b1, z1);
    k_stats<<<dim3((BB * LL1) / 256, 8), 256, 0, stream>>>(z1, BB * LL1, sum1, sumsq1);
    k2_mfma<<<PP / 128, 256, 0, stream>>>(z1, sum1, sumsq1, a1, bfr2, b2, z2T);
    k3_fused<<<BB, 256, 0, stream>>>(z2T, a2, W3, b3, mask, flag, wbufT);
    k4_scale<<<(PP * DD) / (256 * 4), 256, 0, stream>>>(wbufT, facts, out);
}

// Round 5
// 311.710 us; speedup vs baseline: 1.1409x; 1.1409x over previous
//
#include <hip/hip_runtime.h>
#include <hip/hip_bf16.h>
#include <math.h>

#define SS 200
#define BB 1024
#define DD 128
#define FF 512
#define LL1 80
#define LL2 40
#define PP (SS*BB)            // 204800 flattened (s,b) pairs
#define MASK_FILL_F (-4294967295.0f)

typedef short bf16x8 __attribute__((ext_vector_type(8)));
typedef float f32x4  __attribute__((ext_vector_type(4)));

static __device__ __forceinline__ unsigned short f2bf(float x) {
    __hip_bfloat16 h = __float2bfloat16(x);
    return *reinterpret_cast<unsigned short*>(&h);
}
static __device__ __forceinline__ float bf2f(unsigned short u) {
    __hip_bfloat16 h = *reinterpret_cast<__hip_bfloat16*>(&u);
    return __bfloat162float(h);
}
// truncation split: hi = top 16 bits, lo = bf16(x - hi). |err| ~ 2^-16 rel.
static __device__ __forceinline__ void split8(const float* x, bf16x8& ah, bf16x8& al) {
#pragma unroll
    for (int j = 0; j < 8; ++j) {
        unsigned u = __float_as_uint(x[j]);
        ah[j] = (short)(u >> 16);
        float hi = __uint_as_float(u & 0xffff0000u);
        al[j] = (short)f2bf(x[j] - hi);
    }
}

// ---------------------------------------------------------------------------
// Merged prep. blocks 0-29: W1 fold+split -> bfr1 in PHASE-MAJOR order:
//   fid = ((h*6 + step)*2 + hl)*5 + nt,  step = ktL*3+seg, kt = h*2+ktL
//   frag bytes = fid*1024 + lane*16  (one 16B chunk per lane)
// blocks 30-34: W2 pad+split -> bfr2, fid2 = (kt*3+nt)*2+hl.
// block 35: mask layout detect.
__global__ void k_prep_all(const float* __restrict__ W1, const float* __restrict__ W2,
                           const unsigned char* __restrict__ mask,
                           unsigned short* __restrict__ bfr1,
                           unsigned short* __restrict__ bfr2, int* __restrict__ flag) {
    const int blk = blockIdx.x;
    if (blk == 35) {
        if (threadIdx.x == 0) {
            int f = 0;
            for (int i = 0; i < 256; ++i)
                if ((i & 3) && mask[i]) f = 1;
            *flag = f;
        }
        return;
    }
    if (blk < 30) {
        int t = blk * 256 + threadIdx.x;
        if (t >= 120 * 64) return;
        int lane = t & 63;
        int fid  = t >> 6;
        int nt   = fid % 5;
        int hl   = (fid / 5) % 2;
        int step = (fid / 10) % 6;
        int h    = fid / 60;
        int ktL  = step / 3;
        int seg  = step - 3 * ktL;
        int kt   = h * 2 + ktL;
        int n     = nt * 16 + (lane & 15);
        int kbase = kt * 32 + (lane >> 4) * 8;
        unsigned short* o = bfr1 + (size_t)t * 8;
#pragma unroll
        for (int j = 0; j < 8; ++j) {
            int k = kbase + j;
            float w;
            if (seg == 0)      w = W1[k * LL1 + n] + W1[(384 + k) * LL1 + n];
            else if (seg == 1) w = W1[(128 + k) * LL1 + n] - W1[(384 + k) * LL1 + n];
            else               w = W1[(256 + k) * LL1 + n];
            unsigned short hb = f2bf(w);
            o[j] = (hl == 0) ? hb : f2bf(w - bf2f(hb));
        }
    } else {
        int t = (blk - 30) * 256 + threadIdx.x;
        if (t >= 18 * 64) return;
        int lane = t & 63;
        int fid  = t >> 6;
        int hl   = fid & 1;
        int nt   = (fid >> 1) % 3;
        int kt   = fid / 6;
        int n  = nt * 16 + (lane & 15);
        int kb = kt * 32 + (lane >> 4) * 8;
        unsigned short* o = bfr2 + (size_t)t * 8;
#pragma unroll
        for (int j = 0; j < 8; ++j) {
            int k = kb + j;
            float w = (k < LL1 && n < LL2) ? W2[k * LL2 + n] : 0.f;
            unsigned short hb = f2bf(w);
            o[j] = (hl == 0) ? hb : f2bf(w - bf2f(hb));
        }
    }
}

// ---------------------------------------------------------------------------
// K1: z1 = [q | f | q*f] @ foldedW1 + b1 via split-bf16 MFMA 16x16x32.
// B staged in LDS in 2 phases (60 KB each, shared by 4 waves); A loaded in
// per-phase bursts (both kt-steps, 16 outstanding 16B loads); t=2 row-tiles.
__global__ __launch_bounds__(256, 2) void k1_mfma(
    const float* __restrict__ query, const float* __restrict__ facts,
    const unsigned short* __restrict__ bfr, const float* __restrict__ b1,
    float* __restrict__ z1) {
    const int tid  = threadIdx.x;
    const int lane = tid & 63;
    const int m    = lane & 15;
    const int quad = lane >> 4;
    const int pw   = blockIdx.x * 128 + (tid >> 6) * 32;

    __shared__ unsigned short lbuf[30720];   // 61440 B: one phase of B-frags

    f32x4 acc[2][5];
#pragma unroll
    for (int t = 0; t < 2; ++t)
#pragma unroll
        for (int nt = 0; nt < 5; ++nt) acc[t][nt] = (f32x4){0.f, 0.f, 0.f, 0.f};

    int pr[2], qr[2];
#pragma unroll
    for (int t = 0; t < 2; ++t) {
        pr[t] = pw + t * 16 + m;
        qr[t] = pr[t] / SS;
    }

    float q8[2][2][8], f8[2][2][8];    // [ktL][t][j]

#pragma unroll 1
    for (int h = 0; h < 2; ++h) {
        // burst-load A for both kt-steps of this phase (independent of LDS)
#pragma unroll
        for (int ktL = 0; ktL < 2; ++ktL) {
            const int dbase = (h * 2 + ktL) * 32 + quad * 8;
#pragma unroll
            for (int t = 0; t < 2; ++t) {
                *(float4*)&q8[ktL][t][0] = *(const float4*)(query + (size_t)qr[t] * DD + dbase);
                *(float4*)&q8[ktL][t][4] = *(const float4*)(query + (size_t)qr[t] * DD + dbase + 4);
                *(float4*)&f8[ktL][t][0] = *(const float4*)(facts + (size_t)pr[t] * DD + dbase);
                *(float4*)&f8[ktL][t][4] = *(const float4*)(facts + (size_t)pr[t] * DD + dbase + 4);
            }
        }
        if (h) __syncthreads();        // phase-0 LDS reads complete before overwrite
        // stage 61440 B of B-frags: 15 x 16B per thread
        {
            const int4* src = (const int4*)bfr + h * 3840 + tid;
#pragma unroll
            for (int it = 0; it < 15; ++it) {
                int4 v = src[it * 256];
                *(int4*)((char*)lbuf + it * 4096 + tid * 16) = v;
            }
        }
        __syncthreads();

#pragma unroll
        for (int ktL = 0; ktL < 2; ++ktL) {
#pragma unroll
            for (int seg = 0; seg < 3; ++seg) {
                const int step = ktL * 3 + seg;
                bf16x8 Bh[5], Bl[5];
#pragma unroll
                for (int nt = 0; nt < 5; ++nt) {
                    Bh[nt] = *(const bf16x8*)&lbuf[((step * 2 + 0) * 5 + nt) * 512 + lane * 8];
                    Bl[nt] = *(const bf16x8*)&lbuf[((step * 2 + 1) * 5 + nt) * 512 + lane * 8];
                }
#pragma unroll
                for (int t = 0; t < 2; ++t) {
                    float x8[8];
#pragma unroll
                    for (int j = 0; j < 8; ++j)
                        x8[j] = (seg == 0) ? q8[ktL][t][j]
                              : (seg == 1 ? f8[ktL][t][j]
                                          : q8[ktL][t][j] * f8[ktL][t][j]);
                    bf16x8 ah, al;
                    split8(x8, ah, al);
#pragma unroll
                    for (int nt = 0; nt < 5; ++nt) {
                        acc[t][nt] = __builtin_amdgcn_mfma_f32_16x16x32_bf16(ah, Bh[nt], acc[t][nt], 0, 0, 0);
                        acc[t][nt] = __builtin_amdgcn_mfma_f32_16x16x32_bf16(al, Bh[nt], acc[t][nt], 0, 0, 0);
                        acc[t][nt] = __builtin_amdgcn_mfma_f32_16x16x32_bf16(ah, Bl[nt], acc[t][nt], 0, 0, 0);
                    }
                }
            }
        }
    }
    // C/D layout: col = lane&15, row = quad*4 + reg
#pragma unroll
    for (int t = 0; t < 2; ++t)
#pragma unroll
        for (int nt = 0; nt < 5; ++nt) {
            int n = nt * 16 + m;
            float bias = b1[n];
#pragma unroll
            for (int r = 0; r < 4; ++r)
                z1[(size_t)(pw + t * 16 + quad * 4 + r) * LL1 + n] = acc[t][nt][r] + bias;
        }
}

// ---------------------------------------------------------------------------
// Stats for z1: one thread per (b,l) column; streaming unroll-10; writes
// mean and 1/std directly (no atomics, no memset).
__global__ __launch_bounds__(256) void k_msd(
    const float* __restrict__ z, float* __restrict__ mean, float* __restrict__ istd) {
    const int col = blockIdx.x * 256 + threadIdx.x;   // 0 .. 81919
    const float* p = z + col;
    float s = 0.f, q = 0.f;
#pragma unroll 10
    for (int i = 0; i < SS; ++i) {
        float v = p[(size_t)i * (BB * LL1)];
        s += v;
        q = fmaf(v, v, q);
    }
    float mn = s * (1.f / SS);
    float var = (q - (float)SS * mn * mn) * (1.f / (SS - 1));
    mean[col] = mn;
    istd[col] = rsqrtf(var);
}

// ---------------------------------------------------------------------------
// K2: dice1-on-load + split-bf16 MFMA GEMM (K 80->96, N 40->48).
// Full B2 (18 KB) in LDS; t=2 rows; lean registers. Output z2T[b][s][l].
__global__ __launch_bounds__(256, 4) void k2_mfma(
    const float* __restrict__ z1, const float* __restrict__ mean1,
    const float* __restrict__ istd1, const float* __restrict__ a1,
    const unsigned short* __restrict__ bfr2, const float* __restrict__ b2,
    float* __restrict__ z2T) {
    const int tid  = threadIdx.x;
    const int lane = tid & 63;
    const int m    = lane & 15;
    const int quad = lane >> 4;
    const int pw   = blockIdx.x * 128 + (tid >> 6) * 32;
    const float alpha = *a1;

    __shared__ unsigned short lb2[9216];     // 18432 B = all 18 W2 frags
    for (int i = tid; i < 1152; i += 256)
        ((int4*)lb2)[i] = ((const int4*)bfr2)[i];
    __syncthreads();

    f32x4 acc[2][3];
#pragma unroll
    for (int t = 0; t < 2; ++t)
#pragma unroll
        for (int nt = 0; nt < 3; ++nt) acc[t][nt] = (f32x4){0.f, 0.f, 0.f, 0.f};

    float b2v[3];
#pragma unroll
    for (int nt = 0; nt < 3; ++nt) {
        int n = nt * 16 + m;
        b2v[nt] = (n < LL2) ? b2[n] : 0.f;
    }

#pragma unroll
    for (int kt = 0; kt < 3; ++kt) {
        bf16x8 Bh[3], Bl[3];
#pragma unroll
        for (int nt = 0; nt < 3; ++nt) {
            Bh[nt] = *(const bf16x8*)&lb2[((kt * 3 + nt) * 2 + 0) * 512 + lane * 8];
            Bl[nt] = *(const bf16x8*)&lb2[((kt * 3 + nt) * 2 + 1) * 512 + lane * 8];
        }
        const int kb = kt * 32 + quad * 8;
        const bool live = (kt < 2 || quad < 2);
#pragma unroll
        for (int t = 0; t < 2; ++t) {
            const int p = pw + t * 16 + m;
            const int b = p & (BB - 1);
            float x8[8];
            if (live) {
                const float* zr = z1    + (size_t)p * LL1 + kb;
                const float* mu = mean1 + (size_t)b * LL1 + kb;
                const float* is = istd1 + (size_t)b * LL1 + kb;
                float vv[8], mv[8], iv[8];
                *(float4*)&vv[0] = *(const float4*)zr;
                *(float4*)&vv[4] = *(const float4*)(zr + 4);
                *(float4*)&mv[0] = *(const float4*)mu;
                *(float4*)&mv[4] = *(const float4*)(mu + 4);
                *(float4*)&iv[0] = *(const float4*)is;
                *(float4*)&iv[4] = *(const float4*)(is + 4);
#pragma unroll
                for (int j = 0; j < 8; ++j) {
                    float pp = 1.f / (1.f + expf(-(vv[j] - mv[j]) * iv[j]));
                    x8[j] = vv[j] * (alpha + (1.f - alpha) * pp);
                }
            } else {
#pragma unroll
                for (int j = 0; j < 8; ++j) x8[j] = 0.f;
            }
            bf16x8 ah, al;
            split8(x8, ah, al);
#pragma unroll
            for (int nt = 0; nt < 3; ++nt) {
                acc[t][nt] = __builtin_amdgcn_mfma_f32_16x16x32_bf16(ah, Bh[nt], acc[t][nt], 0, 0, 0);
                acc[t][nt] = __builtin_amdgcn_mfma_f32_16x16x32_bf16(al, Bh[nt], acc[t][nt], 0, 0, 0);
                acc[t][nt] = __builtin_amdgcn_mfma_f32_16x16x32_bf16(ah, Bl[nt], acc[t][nt], 0, 0, 0);
            }
        }
    }
#pragma unroll
    for (int t = 0; t < 2; ++t)
#pragma unroll
        for (int r = 0; r < 4; ++r) {
            const int prow = pw + t * 16 + quad * 4 + r;
            const int br = prow & (BB - 1);
            const int sr = prow >> 10;
            float* o = z2T + (size_t)br * (SS * LL2) + (size_t)sr * LL2;
#pragma unroll
            for (int nt = 0; nt < 3; ++nt) {
                int n = nt * 16 + m;
                if (n < LL2) o[n] = acc[t][nt][r] + b2v[nt];
            }
        }
}

// ---------------------------------------------------------------------------
// K3: per b: stage z2T[b] (200x40) to LDS, parallel in-block stats over s,
// dice2, W3 dot, masked softmax over s -> wbufT[b][s].
__global__ __launch_bounds__(256) void k3_fused(
    const float* __restrict__ z2T, const float* __restrict__ a2,
    const float* __restrict__ W3, const float* __restrict__ b3,
    const void* __restrict__ mask, const int* __restrict__ flag,
    float* __restrict__ wbufT) {
    const int b   = blockIdx.x;
    const int tid = threadIdx.x;
    __shared__ float lds[SS * 41];       // stride 41: conflict-free both phases
    __shared__ float psum[6 * LL2], pssq[6 * LL2];
    __shared__ float smean[LL2], sistd[LL2], sw3[LL2];
    __shared__ float red[4];

    const float4* src = (const float4*)(z2T + (size_t)b * (SS * LL2));
    for (int i = tid; i < (SS * LL2) / 4; i += 256) {
        float4 v = src[i];
        int s = i / 10;
        int o = (i - s * 10) * 4;
        float* d = &lds[s * 41 + o];
        d[0] = v.x; d[1] = v.y; d[2] = v.z; d[3] = v.w;
    }
    __syncthreads();
    if (tid < 240) {
        int l = tid % LL2, c = tid / LL2;
        int s0 = c * 34, s1 = (c == 5) ? SS : s0 + 34;
        float sum = 0.f, ssq = 0.f;
        for (int s = s0; s < s1; ++s) {
            float v = lds[s * 41 + l];
            sum += v;
            ssq = fmaf(v, v, ssq);
        }
        psum[c * LL2 + l] = sum;
        pssq[c * LL2 + l] = ssq;
    }
    __syncthreads();
    if (tid < LL2) {
        float sum = 0.f, ssq = 0.f;
#pragma unroll
        for (int c = 0; c < 6; ++c) {
            sum += psum[c * LL2 + tid];
            ssq += pssq[c * LL2 + tid];
        }
        float mean = sum * (1.f / SS);
        float var  = (ssq - (float)SS * mean * mean) * (1.f / (SS - 1));
        smean[tid] = mean;
        sistd[tid] = rsqrtf(var);
        sw3[tid]   = W3[tid];
    }
    __syncthreads();
    const float alpha = *a2;
    const int boolLayout = *flag;

    float logit = -3.0e38f;
    if (tid < SS) {
        float dot = b3[0];
#pragma unroll
        for (int k = 0; k < LL2; ++k) {
            float v  = lds[tid * 41 + k];
            float pp = 1.f / (1.f + expf(-(v - smean[k]) * sistd[k]));
            float h  = v * (pp + alpha * (1.f - pp));
            dot = fmaf(h, sw3[k], dot);
        }
        int mi = tid * BB + b;
        bool mk = boolLayout ? (((const unsigned char*)mask)[mi] != 0)
                             : (((const int*)mask)[mi] != 0);
        logit = mk ? dot : MASK_FILL_F;
    }
    float v = logit;
#pragma unroll
    for (int off = 1; off < 64; off <<= 1) v = fmaxf(v, __shfl_xor(v, off, 64));
    if ((tid & 63) == 0) red[tid >> 6] = v;
    __syncthreads();
    float smax = fmaxf(fmaxf(red[0], red[1]), fmaxf(red[2], red[3]));
    __syncthreads();
    float e = (tid < SS) ? expf(logit - smax) : 0.f;
    v = e;
#pragma unroll
    for (int off = 1; off < 64; off <<= 1) v += __shfl_xor(v, off, 64);
    if ((tid & 63) == 0) red[tid >> 6] = v;
    __syncthreads();
    float inv = 1.f / (red[0] + red[1] + red[2] + red[3]);
    if (tid < SS) wbufT[(size_t)b * SS + tid] = e * inv;
}

// ---------------------------------------------------------------------------
// K4: out[s][b][d] = wbufT[b][s] * facts[s][b][d]
__global__ __launch_bounds__(256) void k4_scale(
    const float* __restrict__ wbufT, const float* __restrict__ facts,
    float* __restrict__ out) {
    int i = blockIdx.x * 256 + threadIdx.x;   // float4 index
    int p = i >> 5;                           // (s*B + b), 32 float4 per row
    float w = wbufT[(size_t)(p & (BB - 1)) * SS + (p >> 10)];
    float4 f = ((const float4*)facts)[i];
    float4 o;
    o.x = f.x * w; o.y = f.y * w; o.z = f.z * w; o.w = f.w * w;
    ((float4*)out)[i] = o;
}

// ---------------------------------------------------------------------------
extern "C" void kernel_launch(void* const* d_in, const int* in_sizes, int n_in,
                              void* d_out, int out_size, void* d_ws, size_t ws_size,
                              hipStream_t stream) {
    const float* query = (const float*)d_in[0];
    const float* facts = (const float*)d_in[1];
    const void*  mask  = d_in[2];
    const float* W1 = (const float*)d_in[3];
    const float* b1 = (const float*)d_in[4];
    const float* a1 = (const float*)d_in[5];
    const float* W2 = (const float*)d_in[6];
    const float* b2 = (const float*)d_in[7];
    const float* a2 = (const float*)d_in[8];
    const float* W3 = (const float*)d_in[9];
    const float* b3 = (const float*)d_in[10];
    float* out = (float*)d_out;

    // d_out scratch (26,214,400 floats; all dead before k4 overwrites):
    //   z1 [0, 16,384,000) ; z2T [16,384,000, 24,576,000) (layout [b][s][l])
    //   mean1 @24,576,000 ; istd1 @24,657,920 ; bfr1 @24,739,840 ; bfr2 @24,801,280
    float* z1  = out;
    float* z2T = out + (size_t)PP * LL1;
    float* mean1 = out + 24576000;
    float* istd1 = out + 24657920;
    unsigned short* bfr1 = (unsigned short*)(out + 24739840);
    unsigned short* bfr2 = (unsigned short*)(out + 24801280);
    float* wbufT = (float*)d_ws;
    int*   flag  = (int*)((char*)d_ws + 900 * 1024);

    k_prep_all<<<36, 256, 0, stream>>>(W1, W2, (const unsigned char*)mask, bfr1, bfr2, flag);
    k1_mfma<<<PP / 128, 256, 0, stream>>>(query, facts, bfr1, b1, z1);
    k_msd<<<(BB * LL1) / 256, 256, 0, stream>>>(z1, mean1, istd1);
    k2_mfma<<<PP / 128, 256, 0, stream>>>(z1, mean1, istd1, a1, bfr2, b2, z2T);
    k3_fused<<<BB, 256, 0, stream>>>(z2T, a2, W3, b3, mask, flag, wbufT);
    k4_scale<<<(PP * DD) / (256 * 4), 256, 0, stream>>>(wbufT, facts, out);
}